// Round 1
// 2532.509 us; speedup vs baseline: 3.1395x; 3.1395x over previous
//
#include <hip/hip_runtime.h>

// JANET layer: T=2048, B=64, I=256, H=256.
// Phase 1: xfh[row][0:256] = seq_row @ W_f + b_f ; xfh[row][256:512] = seq_row @ W_h + b_h
// Phase 2: per-batch sequential recurrence.
//   KEY FIX vs prior version: prior kernel needed 256 f32 VGPRs for the U slice
//   but only 128 were allocated -> compiler demoted U, re-fetched ~512KB/block
//   per step through vmem on the serial critical path (VALUBusy 6.6%, 3.6us/step).
//   Now U is packed as fp16 pairs (half2 u2[8][16] = 128 VGPRs) and consumed with
//   v_dot2_f32_f16 (f32 accumulate). h is staged in LDS as fp16 (4x ds_read_b128
//   per thread per step). xfh workspace moves bf16 -> fp16 (same bytes, 8x more
//   mantissa).

#define T_STEPS 2048
#define BATCH   64
#define NCOL    512

typedef _Float16 half_t;
typedef half_t half2_t __attribute__((ext_vector_type(2)));
typedef half_t half4_t __attribute__((ext_vector_type(4)));

__device__ __forceinline__ float4 ld4(const float* p) { return *(const float4*)p; }
__device__ __forceinline__ void fma4(float4& acc, float s, const float4& v) {
  acc.x = fmaf(s, v.x, acc.x); acc.y = fmaf(s, v.y, acc.y);
  acc.z = fmaf(s, v.z, acc.z); acc.w = fmaf(s, v.w, acc.w);
}

__device__ __forceinline__ void store_xt(float* p, const float4& v) { *(float4*)p = v; }
__device__ __forceinline__ void store_xt(half_t* p, const float4& v) {
  half4_t h;
  h.x = (half_t)v.x; h.y = (half_t)v.y; h.z = (half_t)v.z; h.w = (half_t)v.w;
  *(half4_t*)p = h;   // 8B store, offsets are multiples of 4 elements
}
__device__ __forceinline__ float xload(const float* p) { return *p; }
__device__ __forceinline__ float xload(const half_t* p) { return (float)*p; }

#if __has_builtin(__builtin_amdgcn_fdot2)
__device__ __forceinline__ float fdot2(half2_t a, half2_t b, float c) {
  return __builtin_amdgcn_fdot2(a, b, c, false);   // v_dot2_f32_f16
}
#else
__device__ __forceinline__ float fdot2(half2_t a, half2_t b, float c) {
  return c + (float)a.x * (float)b.x + (float)a.y * (float)b.y;
}
#endif

__device__ __forceinline__ half2_t bcast_h2(float f) {
  return __builtin_bit_cast(half2_t, f);
}

// ---------------- Phase 1: input-projection GEMM ----------------
// M=131072, K=256, N=512. Block computes 128x128; K staged in 32-chunks.
template <typename XT>
__global__ __launch_bounds__(256, 4)
void xproj_gemm(const float* __restrict__ seq,
                const float* __restrict__ Wf, const float* __restrict__ bf,
                const float* __restrict__ Wh, const float* __restrict__ bh,
                XT* __restrict__ xfh)
{
  __shared__ float As[32 * 132];   // A^T: [k][m], pitch 132
  __shared__ float Bs[32 * 132];   // B:   [k][n], pitch 132
  const int tid = threadIdx.x;
  const int mt = blockIdx.x >> 2;
  const int nt = blockIdx.x & 3;
  const int m0 = mt * 128;
  const int n0 = nt * 128;
  const int tm = tid >> 4;   // 0..15
  const int tn = tid & 15;   // 0..15

  float4 acc[8][2];
  #pragma unroll
  for (int i = 0; i < 8; ++i) {
    acc[i][0] = make_float4(0.f, 0.f, 0.f, 0.f);
    acc[i][1] = make_float4(0.f, 0.f, 0.f, 0.f);
  }

  const float* bsrc  = (n0 < 256) ? Wf : Wh;
  const int    bcol0 = (n0 < 256) ? n0 : (n0 - 256);

  for (int kt = 0; kt < 8; ++kt) {
    const int k0 = kt * 32;
    // stage A (128 rows x 32 k), transposed into As[k][m]
    #pragma unroll
    for (int p = 0; p < 4; ++p) {
      int idx = p * 256 + tid;
      int r   = idx >> 3;   // 0..127
      int c4  = idx & 7;    // 0..7
      float4 v = ld4(seq + (size_t)(m0 + r) * 256 + k0 + c4 * 4);
      As[(c4*4+0)*132 + r] = v.x;
      As[(c4*4+1)*132 + r] = v.y;
      As[(c4*4+2)*132 + r] = v.z;
      As[(c4*4+3)*132 + r] = v.w;
    }
    // stage B (32 k x 128 n)
    #pragma unroll
    for (int p = 0; p < 4; ++p) {
      int idx = p * 256 + tid;
      int kr  = idx >> 5;   // 0..31
      int c4  = idx & 31;   // 0..31
      float4 v = ld4(bsrc + (size_t)(k0 + kr) * 256 + bcol0 + c4 * 4);
      *(float4*)&Bs[kr*132 + c4*4] = v;
    }
    __syncthreads();
    #pragma unroll
    for (int k = 0; k < 32; ++k) {
      float4 a0 = ld4(&As[k*132 + tm*4]);
      float4 a1 = ld4(&As[k*132 + 64 + tm*4]);
      float4 b0 = ld4(&Bs[k*132 + tn*4]);
      float4 b1 = ld4(&Bs[k*132 + 64 + tn*4]);
      float ar[8] = {a0.x, a0.y, a0.z, a0.w, a1.x, a1.y, a1.z, a1.w};
      #pragma unroll
      for (int i = 0; i < 8; ++i) {
        fma4(acc[i][0], ar[i], b0);
        fma4(acc[i][1], ar[i], b1);
      }
    }
    __syncthreads();
  }

  const float* bias_src = (n0 < 256) ? bf : bh;
  float4 bias0 = ld4(bias_src + bcol0 + tn*4);
  float4 bias1 = ld4(bias_src + bcol0 + 64 + tn*4);
  #pragma unroll
  for (int i = 0; i < 8; ++i) {
    int m = m0 + ((i < 4) ? (tm*4 + i) : (64 + tm*4 + (i - 4)));
    float4 r0 = acc[i][0];
    r0.x += bias0.x; r0.y += bias0.y; r0.z += bias0.z; r0.w += bias0.w;
    float4 r1 = acc[i][1];
    r1.x += bias1.x; r1.y += bias1.y; r1.z += bias1.z; r1.w += bias1.w;
    store_xt(xfh + (size_t)m * NCOL + n0 + tn*4,      r0);
    store_xt(xfh + (size_t)m * NCOL + n0 + 64 + tn*4, r1);
  }
}

// ---------------- Phase 2: sequential recurrence ----------------
// 64 blocks (one per batch) x 512 threads. Thread tid owns output column
// j = tid of combined [U_f | U_h] (j<256: forget gate; j>=256: candidate).
// U slice held as fp16 pairs: half2 u2[8][16] = 128 VGPRs (FITS, unlike the
// prior 256-VGPR f32 version). Matvec = 128 x v_dot2_f32_f16 per thread.
template <typename XT>
__global__ __launch_bounds__(512, 2)
void janet_rec(const float* __restrict__ Uf, const float* __restrict__ Uh,
               const XT* __restrict__ xfh, const float* __restrict__ pa,
               float* __restrict__ out)
{
  __shared__ __align__(16) half_t h_lds[256];  // h_{t-1} in fp16 for the matvec
  __shared__ float g_lds[256];
  const int tid = threadIdx.x;
  const int b   = blockIdx.x;
  const int kg  = tid & 7;          // k-group 0..7 (k in [kg*32, kg*32+32))
  const int jg  = tid >> 3;         // 0..63
  const int j0  = jg * 8;           // this thread's 8 output columns

  const float* Usrc = (j0 < 256) ? (Uf + j0) : (Uh + (j0 - 256));
  // u2[j][p] = (U[k][j0+j], U[k+1][j0+j]) with k = kg*32 + 2p
  half2_t u2[8][16];
  #pragma unroll
  for (int p = 0; p < 16; ++p) {
    const int k = kg * 32 + 2 * p;
    #pragma unroll
    for (int j = 0; j < 8; ++j) {
      half2_t w;
      w.x = (half_t)Usrc[(size_t)k * 256 + j];
      w.y = (half_t)Usrc[(size_t)(k + 1) * 256 + j];
      u2[j][p] = w;
    }
  }

  const float aprelu = pa[0];
  if (tid < 256) h_lds[tid] = (half_t)0.f;   // h_{-1}=0 makes step 0 the general step
  float h_old = 0.f;
  __syncthreads();

  // x prefetched one full step ahead (vmem latency hides under the matvec)
  float x = xload(xfh + (size_t)b * NCOL + tid);

  for (int t = 0; t < T_STEPS; ++t) {
    float x_next = 0.f;
    if (t + 1 < T_STEPS)
      x_next = xload(xfh + ((size_t)(t + 1) * BATCH + b) * NCOL + tid);

    // this thread's 32 h values (fp16) via 4x ds_read_b128
    const float4* hv4 = (const float4*)(h_lds + kg * 32);
    float4 ha = hv4[0], hb = hv4[1], hc = hv4[2], hd = hv4[3];
    half2_t hp[16];
    hp[0]  = bcast_h2(ha.x); hp[1]  = bcast_h2(ha.y);
    hp[2]  = bcast_h2(ha.z); hp[3]  = bcast_h2(ha.w);
    hp[4]  = bcast_h2(hb.x); hp[5]  = bcast_h2(hb.y);
    hp[6]  = bcast_h2(hb.z); hp[7]  = bcast_h2(hb.w);
    hp[8]  = bcast_h2(hc.x); hp[9]  = bcast_h2(hc.y);
    hp[10] = bcast_h2(hc.z); hp[11] = bcast_h2(hc.w);
    hp[12] = bcast_h2(hd.x); hp[13] = bcast_h2(hd.y);
    hp[14] = bcast_h2(hd.z); hp[15] = bcast_h2(hd.w);

    float acc[8];
    #pragma unroll
    for (int j = 0; j < 8; ++j) acc[j] = 0.f;
    #pragma unroll
    for (int p = 0; p < 16; ++p) {
      const half2_t hv = hp[p];
      #pragma unroll
      for (int j = 0; j < 8; ++j)
        acc[j] = fdot2(hv, u2[j][p], acc[j]);
    }

    // reduce the 8 partials across kg lanes; lane kg keeps column j0+kg == tid
    float s00 = acc[0] + __shfl_xor(acc[0], 1);
    float s01 = acc[1] + __shfl_xor(acc[1], 1);
    float s02 = acc[2] + __shfl_xor(acc[2], 1);
    float s03 = acc[3] + __shfl_xor(acc[3], 1);
    float s04 = acc[4] + __shfl_xor(acc[4], 1);
    float s05 = acc[5] + __shfl_xor(acc[5], 1);
    float s06 = acc[6] + __shfl_xor(acc[6], 1);
    float s07 = acc[7] + __shfl_xor(acc[7], 1);
    const bool sb0 = (kg & 1);
    float r0 = sb0 ? s01 : s00;
    float r1 = sb0 ? s03 : s02;
    float r2 = sb0 ? s05 : s04;
    float r3 = sb0 ? s07 : s06;
    r0 += __shfl_xor(r0, 2);
    r1 += __shfl_xor(r1, 2);
    r2 += __shfl_xor(r2, 2);
    r3 += __shfl_xor(r3, 2);
    const bool sb1 = (kg & 2);
    float q0 = sb1 ? r1 : r0;
    float q1 = sb1 ? r3 : r2;
    q0 += __shfl_xor(q0, 4);
    q1 += __shfl_xor(q1, 4);
    const float s = (kg & 4) ? q1 : q0;

    const float pre = s + x;
    float f = 0.f;
    if (tid < 256) {                 // wave-uniform branch (waves 0-3)
      f = __builtin_amdgcn_rcpf(1.f + __expf(-pre));          // sigmoid
    } else {                         // waves 4-7: candidate tanh
      float e2 = __expf(2.f * pre);
      float g  = 1.f - 2.f * __builtin_amdgcn_rcpf(e2 + 1.f); // tanh
      g_lds[tid - 256] = g;
    }
    __syncthreads();
    if (tid < 256) {
      float g  = g_lds[tid];
      float hn = fmaf(f, h_old - g, g);        // f*h + (1-f)*g
      hn = (hn >= 0.f) ? hn : aprelu * hn;     // prelu
      h_old = hn;                              // exact f32 state
      h_lds[tid] = (half_t)hn;                 // fp16 copy for next matvec
      out[((size_t)t * BATCH + b) * 256 + tid] = hn;
    }
    __syncthreads();
    x = x_next;
  }
}

extern "C" void kernel_launch(void* const* d_in, const int* in_sizes, int n_in,
                              void* d_out, int out_size, void* d_ws, size_t ws_size,
                              hipStream_t stream) {
  const float* seq = (const float*)d_in[0];
  const float* Wf  = (const float*)d_in[1];
  const float* Uf  = (const float*)d_in[2];
  const float* bf  = (const float*)d_in[3];
  const float* Wh  = (const float*)d_in[4];
  const float* Uh  = (const float*)d_in[5];
  const float* bh  = (const float*)d_in[6];
  const float* pa  = (const float*)d_in[7];
  float* out = (float*)d_out;

  const size_t rows = (size_t)T_STEPS * BATCH;
  const size_t need_f32 = rows * NCOL * sizeof(float);   // 256 MiB

  dim3 g1(4096), blk1(256);
  dim3 g2(BATCH), blk2(512);

  if (ws_size >= need_f32) {
    float* xfh = (float*)d_ws;
    hipLaunchKernelGGL(xproj_gemm<float>, g1, blk1, 0, stream, seq, Wf, bf, Wh, bh, xfh);
    hipLaunchKernelGGL(janet_rec<float>,  g2, blk2, 0, stream, Uf, Uh, xfh, pa, out);
  } else {
    half_t* xfh = (half_t*)d_ws;
    hipLaunchKernelGGL(xproj_gemm<half_t>, g1, blk1, 0, stream, seq, Wf, bf, Wh, bh, xfh);
    hipLaunchKernelGGL(janet_rec<half_t>,  g2, blk2, 0, stream, Uf, Uh, xfh, pa, out);
  }
}